// Round 10
// baseline (220.202 us; speedup 1.0000x reference)
//
#include <hip/hip_runtime.h>

// Box3dAttention: B=2, LQ=4096, d=256, heads=8, head_dim=32, 5x5=25 points,
// feature map 188x188 (LV=35344).
//
// Round 18 == round 17 resubmitted verbatim (round-17 bench failed on
// GPUAcquisitionTimeout; kernel never ran).
//
// Round 17:
//  (a) K1 (gemm_vproj): SAME byte-minimal B-resident structure as r16, but
//      1024 threads = 16 waves/CU (was 8). Seven K1 structures all measured
//      >=43us with Occupancy ~15% and nothing saturated -> latency-bound,
//      under-TLP'd. Wave tile 16x64 (acc 16 VGPR), A-stage 1 float4/thread,
//      identical MFMA order & swizzles -> bitwise-same Vout.
//  (b) K0+K2 merged into one prep_kernel (blocks 0-511 logits, 512-543
//      converts). Wab/bab deleted: K2 reads W_attn/W_box/b_attn/b_box with
//      the identical row-select inline (numerically identical). Removes the
//      K0->K2 dependency and one dispatch; converts hide under K2 VALU.
//  (c) K3/K4 unchanged (r16-verified).
//
// Pipeline:
//  P  prep       : [0,512) logits = query @ sel(W)^T + sel(b) (fp32 VALU)
//                  [512,544) W_value/W_out -> bf16
//  K1 gemm_vproj : value fp32 @ wvbf^T + b_value -> Vout bf16 head-major
//  K3 decode_sample: XCD-temporal remap fused decode+gather
//  K4 gemm_out   : ohbf @ wobf^T + b_out -> out fp32

typedef float floatx4 __attribute__((ext_vector_type(4)));
typedef short shortx8 __attribute__((ext_vector_type(8)));

static __device__ __forceinline__ unsigned short f2bf(float x) {
    unsigned int u = __float_as_uint(x);
    return (unsigned short)((u + 0x7fffu + ((u >> 16) & 1u)) >> 16);
}
static __device__ __forceinline__ unsigned int pack2(float a, float b) {
    return (unsigned int)f2bf(a) | ((unsigned int)f2bf(b) << 16);
}
static __device__ __forceinline__ void async16(const void* g, void* lds) {
    __builtin_amdgcn_global_load_lds(
        (const __attribute__((address_space(1))) unsigned int*)g,
        (__attribute__((address_space(3))) unsigned int*)lds, 16, 0, 0);
}

// ---------------- P: fused logits (K2) + weight converts (K0) ----------------
// blocks [0,512): logits tile 64x64 (identical math to old gemm_nt_bias on the
//                 padded Wab/bab, with the pad select done inline).
// blocks [512,528): W_value -> bf16.  [528,544): W_out -> bf16.
__global__ __launch_bounds__(256) void prep_kernel(
    const float* __restrict__ query,
    const float* __restrict__ W_attn, const float* __restrict__ W_box,
    const float* __restrict__ b_attn, const float* __restrict__ b_box,
    float* __restrict__ logits, int MQ,
    const float* __restrict__ W_value, unsigned short* __restrict__ wvbf,
    const float* __restrict__ W_out, unsigned short* __restrict__ wobf)
{
    const int blk = blockIdx.x, tid = threadIdx.x;
    if (blk < 512) {
        const int K = 256, N = 256, M = MQ;
        __shared__ float As[16][68];
        __shared__ float Bs[16][68];
        int tcol = tid & 15, trow = tid >> 4;
        int m0 = (blk & 127) * 64, n0 = (blk >> 7) * 64;
        int lr = tid >> 2, lc = (tid & 3) << 2;
        float acc[4][4] = {};
        for (int k0 = 0; k0 < K; k0 += 16) {
            int arow = m0 + lr; if (arow > M - 1) arow = M - 1;
            float4 av = *(const float4*)(query + (size_t)arow * K + k0 + lc);
            int r = n0 + lr;
            float4 wv;
            if (r < 200)      wv = *(const float4*)(W_attn + (size_t)r * 256 + k0 + lc);
            else if (r < 240) wv = *(const float4*)(W_box + (size_t)(r - 200) * 256 + k0 + lc);
            else              wv = make_float4(0.f, 0.f, 0.f, 0.f);
            __syncthreads();
            As[lc + 0][lr] = av.x; As[lc + 1][lr] = av.y; As[lc + 2][lr] = av.z; As[lc + 3][lr] = av.w;
            Bs[lc + 0][lr] = wv.x; Bs[lc + 1][lr] = wv.y; Bs[lc + 2][lr] = wv.z; Bs[lc + 3][lr] = wv.w;
            __syncthreads();
#pragma unroll
            for (int k = 0; k < 16; ++k) {
                float4 a4 = *(const float4*)&As[k][trow << 2];
                float4 b4 = *(const float4*)&Bs[k][tcol << 2];
                float a[4] = {a4.x, a4.y, a4.z, a4.w};
                float bb[4] = {b4.x, b4.y, b4.z, b4.w};
#pragma unroll
                for (int i = 0; i < 4; i++)
#pragma unroll
                    for (int j = 0; j < 4; j++) acc[i][j] += a[i] * bb[j];
            }
        }
#pragma unroll
        for (int i = 0; i < 4; i++) {
            int m = m0 + trow * 4 + i;
            if (m >= M) continue;
#pragma unroll
            for (int j = 0; j < 4; j++) {
                int n = n0 + tcol * 4 + j;
                float bb = n < 200 ? b_attn[n] : (n < 240 ? b_box[n - 200] : 0.f);
                logits[(size_t)m * N + n] = acc[i][j] + bb;
            }
        }
    } else if (blk < 528) {
        int base = (blk - 512) * 1024 + tid;
#pragma unroll
        for (int k = 0; k < 4; ++k) {
            int j = base + k * 256;
            float4 f = ((const float4*)W_value)[j];
            ((uint2*)wvbf)[j] = make_uint2(pack2(f.x, f.y), pack2(f.z, f.w));
        }
    } else {
        int base = (blk - 528) * 1024 + tid;
#pragma unroll
        for (int k = 0; k < 4; ++k) {
            int j = base + k * 256;
            float4 f = ((const float4*)W_out)[j];
            ((uint2*)wobf)[j] = make_uint2(pack2(f.x, f.y), pack2(f.z, f.w));
        }
    }
}

// ---------------- K1: byte-minimal, 16-wave TLP value projection ----------------
// Vout = value(M x 256 fp32) @ wvbf(256x256 bf16)^T + b_value, head-major bf16.
// 1024 thr = 16 waves (wm=wv&3: 16-row m-frag; wn=wv>>2: 64-col n-quarter).
// B resident in LDS [256 rows][32 granules], granule g at g^(row&7) (via
// pre-swizzled async16 source). A: 64x64 bf16 per kc, 2x8KB dbuf; each thread
// reg-loads ONE float4 fp32 (prefetched one phase ahead), packs (f2bf RNE,
// bitwise-identical), ds_writes 8B at the swizzled granule.
__global__ __launch_bounds__(1024) void gemm_vproj(
    const float* __restrict__ A,
    const unsigned short* __restrict__ Bw,
    const float* __restrict__ bias,
    unsigned short* __restrict__ Vout, int M, int LV)
{
    __shared__ unsigned short Bres[256 * 256];   // 131072 B
    __shared__ unsigned short As[2][64 * 64];    // 2 x 8192 B
    const int tid = threadIdx.x;
    const int wv = tid >> 6, lane = tid & 63;
    const int lr = lane & 15, lq = lane >> 4;
    const int wm = wv & 3, wn = wv >> 2;
    const int rowA = tid >> 4;          // 0..63 (A staging row)
    const int gA4 = tid & 15;           // float4 index within 64 fp32 cols
    const int dstA = rowA * 128 + (((gA4 >> 1) ^ (rowA & 7)) * 16) + (gA4 & 1) * 8;

    // ---- B resident stage: 8192 granules via async16, pre-swizzled source ----
#pragma unroll
    for (int j = 0; j < 8; ++j) {
        int G = j * 1024 + tid;          // = j*1024 + wv*64 + lane
        int row = G >> 5, g = G & 31;
        async16(Bw + (size_t)row * 256 + (g ^ (row & 7)) * 8,
                (char*)Bres + j * 16384 + wv * 1024);   // + lane*16 by HW
    }

    const int niter = (M + 63) / 64;
    const int stride = gridDim.x;

    // ---- prologue: A(it0, kc=0) regs -> pack -> As[0] ----
    int it0 = blockIdx.x;
    float4 pf;
    {
        int ra = it0 * 64 + rowA; ra = ra < M ? ra : M - 1;
        pf = *(const float4*)(A + (size_t)ra * 256 + gA4 * 4);
        *(uint2*)((char*)As[0] + dstA) = make_uint2(pack2(pf.x, pf.y), pack2(pf.z, pf.w));
    }
    __syncthreads();   // drains B asyncs + A ds_writes

    int buf = 0;
    for (int it = it0; it < niter; it += stride) {
        const int m0 = it * 64;
        floatx4 acc[4];
#pragma unroll
        for (int j = 0; j < 4; ++j) acc[j] = (floatx4){0.f, 0.f, 0.f, 0.f};

#pragma unroll
        for (int kc = 0; kc < 4; ++kc) {
            // ---- prefetch next A phase (kc+1, or next iter kc=0) ----
            int nit = it, nkc = kc + 1;
            if (nkc == 4) { nkc = 0; nit = it + stride; if (nit >= niter) nit = it; }
            {
                int ra = nit * 64 + rowA; ra = ra < M ? ra : M - 1;
                pf = *(const float4*)(A + (size_t)ra * 256 + nkc * 64 + gA4 * 4);
            }
            // ---- compute on As[buf] x Bres[kc panel] ----
#pragma unroll
            for (int kb = 0; kb < 2; ++kb) {
                shortx8 af, bfr[4];
                {
                    int arow = wm * 16 + lr;
                    af = *(const shortx8*)((const char*)As[buf] + arow * 128 +
                                           (((kb * 4 + lq) ^ (arow & 7)) * 16));
                }
#pragma unroll
                for (int t = 0; t < 4; ++t) {
                    int brow = wn * 64 + t * 16 + lr;
                    int gg = kc * 8 + kb * 4 + lq;
                    bfr[t] = *(const shortx8*)((const char*)Bres + brow * 512 +
                                               ((gg ^ (brow & 7)) * 16));
                }
#pragma unroll
                for (int tj = 0; tj < 4; ++tj)
                    acc[tj] = __builtin_amdgcn_mfma_f32_16x16x32_bf16(bfr[tj], af, acc[tj], 0, 0, 0);
            }
            // ---- pack + write next A phase into As[buf^1] ----
            *(uint2*)((char*)As[buf ^ 1] + dstA) = make_uint2(pack2(pf.x, pf.y), pack2(pf.z, pf.w));
            __syncthreads();
            buf ^= 1;
        }
        // ---- epilogue: head-major bf16 store (transposed D) ----
        {
            int m = m0 + wm * 16 + lr;
            if (m < M) {
                int b = m >= LV ? 1 : 0;
                int lv = m - (b ? LV : 0);
#pragma unroll
                for (int tj = 0; tj < 4; ++tj) {
                    int nb = wn * 64 + tj * 16 + lq * 4;
                    float4 bv = *(const float4*)(bias + nb);
                    int h = nb >> 5, dh = nb & 31;
                    unsigned short* dst = Vout + ((size_t)(b * 8 + h) * LV + lv) * 32 + dh;
                    *(uint2*)dst = make_uint2(pack2(acc[tj][0] + bv.x, acc[tj][1] + bv.y),
                                              pack2(acc[tj][2] + bv.z, acc[tj][3] + bv.w));
                }
            }
        }
    }
}

// ---------------- K3: XCD-temporal fused decode + bilinear gather ----------------
__global__ __launch_bounds__(256) void decode_sample_kernel(
    const unsigned short* __restrict__ v,   // bf16 [b*8+h][LV][32]
    const float* __restrict__ logits,       // MQ x 256 (240 real)
    const float* __restrict__ ref_windows,  // MQ x 7
    float* __restrict__ attn_out,           // MQ x 200
    unsigned short* __restrict__ ohbf,      // MQ x 256 bf16
    const int* __restrict__ Hf_p, const int* __restrict__ Wf_p, int LV, int LQ)
{
    __shared__ float lg[8][32];
    __shared__ float rw[8][7];
    __shared__ float prm[8][6];
    __shared__ float mxinv[8][2];
    __shared__ uint4 pk[8][25][2];

    const int lin = blockIdx.y * 16 + blockIdx.x;
    const int nc = gridDim.y;               // LQ/8
    const int seq = lin >> 3;
    const int c = seq % nc;
    const int s = (lin & 7) + ((seq / nc) << 3);
    const int b = s >> 3, h = s & 7;
    const int tid = threadIdx.x;
    const int Hf = *Hf_p, Wf = *Wf_p;
    const size_t mbase = (size_t)b * LQ + c * 8;

    if (tid < 240) {
        int qq = tid / 30, j = tid - qq * 30;
        int col = (j < 25) ? h * 25 + j : 200 + h * 5 + (j - 25);
        lg[qq][j] = logits[(mbase + qq) * 256 + col];
    }
    if (tid < 56) {
        int qq = tid / 7, k = tid - qq * 7;
        rw[qq][k] = ref_windows[(mbase + qq) * 7 + k];
    }
    __syncthreads();

    if (tid < 8) {
        int qq = tid;
        float mx = -1e30f;
#pragma unroll
        for (int p = 0; p < 25; p++) mx = fmaxf(mx, lg[qq][p]);
        float ssum = 0.f;
#pragma unroll
        for (int p = 0; p < 25; p++) ssum += expf(lg[qq][p] - mx);
        mxinv[qq][0] = mx; mxinv[qq][1] = 1.f / ssum;
        float cx = rw[qq][0] + lg[qq][25] * 0.125f * rw[qq][3];
        float cy = rw[qq][1] + lg[qq][26] * 0.125f * rw[qq][4];
        float bw = rw[qq][3] + lg[qq][27] * 0.125f * rw[qq][3];
        float bh = rw[qq][4] + lg[qq][28] * 0.125f * rw[qq][4];
        float ang = (rw[qq][6] + lg[qq][29] * 0.0625f) * 6.283185307179586f;
        prm[qq][0] = cx; prm[qq][1] = cy;
        prm[qq][2] = fmaxf(bw, 0.f); prm[qq][3] = fmaxf(bh, 0.f);
        prm[qq][4] = cosf(ang); prm[qq][5] = sinf(ang);
    }
    __syncthreads();

    if (tid < 200) {
        int qq = tid / 25, p = tid - qq * 25;
        float a = expf(lg[qq][p] - mxinv[qq][0]) * mxinv[qq][1];
        attn_out[(mbase + qq) * 200 + h * 25 + p] = a;
        int pi = p / 5, pj = p - pi * 5;
        float g0 = (float)(pj - 2) * 0.2f * prm[qq][2];
        float g1 = (float)(pi - 2) * 0.2f * prm[qq][3];
        float ca = prm[qq][4], sa = prm[qq][5];
        float gx = (prm[qq][0] + g0 * ca - g1 * sa) * (float)Wf - 0.5f;
        float gy = (prm[qq][1] + g0 * sa + g1 * ca) * (float)Hf - 0.5f;
        float x0f = floorf(gx), y0f = floorf(gy);
        int x0 = (int)x0f, y0 = (int)y0f;
        float wx1 = gx - x0f, wy1 = gy - y0f;
        float wx0 = 1.f - wx1, wy0 = 1.f - wy1;
        int y1 = y0 + 1;
        int bx; float wl, wr;
        if (x0 >= 0 && x0 <= Wf - 2)      { bx = x0;     wl = wx0; wr = wx1; }
        else if (x0 == -1)                { bx = 0;      wl = wx1; wr = 0.f; }
        else if (x0 == Wf - 1)            { bx = Wf - 2; wl = 0.f; wr = wx0; }
        else                              { bx = 0;      wl = 0.f; wr = 0.f; }
        float wy0v = (y0 >= 0 && y0 < Hf) ? wy0 : 0.f;
        float wy1v = (y1 >= 0 && y1 < Hf) ? wy1 : 0.f;
        int cy0 = min(max(y0, 0), Hf - 1), cy1 = min(max(y1, 0), Hf - 1);
        unsigned off0 = (unsigned)(cy0 * Wf + bx) * 16u;
        unsigned off1 = (unsigned)(cy1 * Wf + bx) * 16u;
        float aw0 = a * wy0v, aw1 = a * wy1v;
        pk[qq][p][0] = make_uint4(__float_as_uint(aw0 * wl), __float_as_uint(aw1 * wl), off0, off1);
        pk[qq][p][1] = make_uint4(__float_as_uint(aw0 * wr), __float_as_uint(aw1 * wr), off0, off1);
    }
    __syncthreads();

    const int qq = tid >> 5, l = tid & 31;
    const unsigned int* vw = (const unsigned int*)(v + (size_t)s * LV * 32);
    const uint4* pkp = &pk[qq][0][l >> 4];
    float e0 = 0.f, o0 = 0.f, e1 = 0.f, o1 = 0.f;
#pragma unroll
    for (int p = 0; p < 25; ++p) {
        uint4 t = pkp[2 * p];
        float w0 = __uint_as_float(t.x), w1 = __uint_as_float(t.y);
        unsigned u0 = vw[t.z + l];
        unsigned u1 = vw[t.w + l];
        e0 += w0 * __uint_as_float(u0 << 16);
        o0 += w0 * __uint_as_float(u0 & 0xffff0000u);
        e1 += w1 * __uint_as_float(u1 << 16);
        o1 += w1 * __uint_as_float(u1 & 0xffff0000u);
    }
    float a0 = e0 + e1, a1 = o0 + o1;
    a0 += __shfl_xor(a0, 16, 32);
    a1 += __shfl_xor(a1, 16, 32);
    if (l < 16)
        ((unsigned int*)ohbf)[(mbase + qq) * 128 + h * 16 + l] = pack2(a0, a1);
}

// ---------------- K4: bf16 MFMA GEMM (round-11 verified, BM=64) ----------------
__global__ __launch_bounds__(256) void gemm_out(
    const unsigned short* __restrict__ Ab,
    const unsigned short* __restrict__ Bw,
    const float* __restrict__ bias,
    float* __restrict__ C, int M)
{
    constexpr int BM = 64;
    constexpr int NI = BM / 32, TI = BM / 32;
    __shared__ unsigned short As[2][BM * 64];
    __shared__ unsigned short Bs[2][128 * 64];
    const int tid = threadIdx.x;
    const int wv = tid >> 6, lane = tid & 63;
    const int lr = lane & 15, lq = lane >> 4;
    const int m0 = blockIdx.x * BM, n0 = blockIdx.y * 128;
    const int wm = wv & 1, wn = wv >> 1;
    const int srow = tid >> 3;
    const int colg = tid & 7;
    const int colgSw = colg ^ (srow & 7);

    floatx4 acc[TI][4];
#pragma unroll
    for (int i = 0; i < TI; ++i)
#pragma unroll
        for (int j = 0; j < 4; ++j) acc[i][j] = (floatx4){0.f, 0.f, 0.f, 0.f};

    auto compute = [&](const unsigned short* Acur, const unsigned short* Bcur) {
#pragma unroll
        for (int kb = 0; kb < 2; ++kb) {
            shortx8 af[TI], bfr[4];
#pragma unroll
            for (int t = 0; t < TI; ++t) {
                int arow = wm * (BM / 2) + t * 16 + lr;
                af[t] = *(const shortx8*)&Acur[arow * 64 + (((kb * 4 + lq) ^ (arow & 7)) * 8)];
            }
#pragma unroll
            for (int t = 0; t < 4; ++t) {
                int brow = wn * 64 + t * 16 + lr;
                bfr[t] = *(const shortx8*)&Bcur[brow * 64 + (((kb * 4 + lq) ^ (brow & 7)) * 8)];
            }
#pragma unroll
            for (int ti = 0; ti < TI; ++ti)
#pragma unroll
                for (int tj = 0; tj < 4; ++tj)
                    acc[ti][tj] = __builtin_amdgcn_mfma_f32_16x16x32_bf16(bfr[tj], af[ti], acc[ti][tj], 0, 0, 0);
        }
    };

#pragma unroll
    for (int i = 0; i < NI; ++i) {
        int ra = m0 + i * 32 + srow; ra = ra < M ? ra : M - 1;
        async16(Ab + (size_t)ra * 256 + colgSw * 8, (char*)As[0] + i * 4096 + wv * 1024);
    }
#pragma unroll
    for (int i = 0; i < 4; ++i) {
        int rb = n0 + i * 32 + srow;
        async16(Bw + (size_t)rb * 256 + colgSw * 8, (char*)Bs[0] + i * 4096 + wv * 1024);
    }
    __syncthreads();
    int cur = 0;
    for (int kc = 0; kc < 4; ++kc) {
        const int nk = (kc + 1) * 64;
        if (kc < 3) {
#pragma unroll
            for (int i = 0; i < NI; ++i) {
                int ra = m0 + i * 32 + srow; ra = ra < M ? ra : M - 1;
                async16(Ab + (size_t)ra * 256 + nk + colgSw * 8,
                        (char*)As[cur ^ 1] + i * 4096 + wv * 1024);
            }
#pragma unroll
            for (int i = 0; i < 4; ++i) {
                int rb = n0 + i * 32 + srow;
                async16(Bw + (size_t)rb * 256 + nk + colgSw * 8,
                        (char*)Bs[cur ^ 1] + i * 4096 + wv * 1024);
            }
        }
        compute(As[cur], Bs[cur]);
        __syncthreads();
        cur ^= 1;
    }
#pragma unroll
    for (int ti = 0; ti < TI; ++ti) {
        int m = m0 + wm * (BM / 2) + ti * 16 + lr;
        if (m >= M) continue;
        float* Crow = C + (size_t)m * 256;
#pragma unroll
        for (int tj = 0; tj < 4; ++tj) {
            int nb = n0 + wn * 64 + tj * 16 + lq * 4;
            float4 bv = *(const float4*)(bias + nb);
            float4 o = make_float4(acc[ti][tj][0] + bv.x, acc[ti][tj][1] + bv.y,
                                   acc[ti][tj][2] + bv.z, acc[ti][tj][3] + bv.w);
            *(float4*)(Crow + nb) = o;
        }
    }
}

extern "C" void kernel_launch(void* const* d_in, const int* in_sizes, int n_in,
                              void* d_out, int out_size, void* d_ws, size_t ws_size,
                              hipStream_t stream) {
    const float* query       = (const float*)d_in[0];
    const float* value       = (const float*)d_in[1];
    const float* ref_windows = (const float*)d_in[2];
    const float* W_box       = (const float*)d_in[3];
    const float* b_box       = (const float*)d_in[4];
    const float* W_attn      = (const float*)d_in[5];
    const float* b_attn      = (const float*)d_in[6];
    const float* W_value     = (const float*)d_in[7];
    const float* b_value     = (const float*)d_in[8];
    const float* W_out       = (const float*)d_in[9];
    const float* b_out       = (const float*)d_in[10];
    const int*   Hf          = (const int*)d_in[11];
    const int*   Wf          = (const int*)d_in[12];

    const int M1 = in_sizes[1] / 256;  // B*LV = 70688
    const int MQ = in_sizes[0] / 256;  // B*LQ = 8192
    const int LQ = MQ / 2;
    const int LV = M1 / 2;

    unsigned short* Vout = (unsigned short*)d_ws;                 // M1*256
    unsigned short* ohbf = Vout + (size_t)M1 * 256;               // MQ*256
    unsigned short* wvbf = ohbf + (size_t)MQ * 256;               // 65536
    unsigned short* wobf = wvbf + 65536;                          // 65536
    float* logits    = (float*)(wobf + 65536);                    // MQ*256

    float* out0     = (float*)d_out;
    float* attn_out = out0 + (size_t)MQ * 256;

    // P: fused logits (512 blocks) + weight converts (32 blocks)
    prep_kernel<<<544, 256, 0, stream>>>(query, W_attn, W_box, b_attn, b_box,
                                         logits, MQ, W_value, wvbf, W_out, wobf);
    // K1: byte-minimal 16-wave value projection (256 blocks = 1/CU)
    gemm_vproj<<<256, 1024, 0, stream>>>(value, wvbf, b_value, Vout, M1, LV);
    // K3: XCD-temporal fused softmax + box decode + gather -> bf16 out_heads
    decode_sample_kernel<<<dim3(16, LQ / 8), 256, 0, stream>>>(
        Vout, logits, ref_windows, attn_out, ohbf, Hf, Wf, LV, LQ);
    // K4: output projection (round-11 verified LDS dbuf kernel)
    dim3 g4(MQ / 64, 2);
    gemm_out<<<g4, 256, 0, stream>>>(ohbf, wobf, b_out, out0, MQ);
}

// Round 11
// 218.658 us; speedup vs baseline: 1.0071x; 1.0071x over previous
//
#include <hip/hip_runtime.h>

// Box3dAttention: B=2, LQ=4096, d=256, heads=8, head_dim=32, 5x5=25 points,
// feature map 188x188 (LV=35344).
//
// Round 19:
//  (a) K1 CLOSED: reverted to r16's 512-thread B-resident gemm_vproj
//      (43.0us, best of 8 structures). r18 proved occupancy doubling
//      (15->31%) does NOT move K1 -> no remaining intra-kernel lever.
//  (b) K3 rebuilt at 2x granularity: 512 thr, 16 q/block, 4096 blocks
//      (was 256 thr, 8 q, 8192). Same per-q math (bitwise identical);
//      per-block fixed costs (logits/rw loads, barriers 6->3 per 16q,
//      serial softmax phase) amortized 2x. K3 is the only kernel never
//      structurally touched and the largest unmeasured unknown.
//  (c) prep (merged K0+K2) and K4 unchanged.
//
// Pipeline:
//  P  prep       : [0,512) logits = query @ sel(W)^T + sel(b) (fp32 VALU)
//                  [512,544) W_value/W_out -> bf16
//  K1 gemm_vproj : value fp32 @ wvbf^T + b_value -> Vout bf16 head-major
//  K3 decode_sample: XCD-temporal remap fused decode+gather (16q blocks)
//  K4 gemm_out   : ohbf @ wobf^T + b_out -> out fp32

typedef float floatx4 __attribute__((ext_vector_type(4)));
typedef short shortx8 __attribute__((ext_vector_type(8)));

static __device__ __forceinline__ unsigned short f2bf(float x) {
    unsigned int u = __float_as_uint(x);
    return (unsigned short)((u + 0x7fffu + ((u >> 16) & 1u)) >> 16);
}
static __device__ __forceinline__ unsigned int pack2(float a, float b) {
    return (unsigned int)f2bf(a) | ((unsigned int)f2bf(b) << 16);
}
static __device__ __forceinline__ void async16(const void* g, void* lds) {
    __builtin_amdgcn_global_load_lds(
        (const __attribute__((address_space(1))) unsigned int*)g,
        (__attribute__((address_space(3))) unsigned int*)lds, 16, 0, 0);
}

// ---------------- P: fused logits (K2) + weight converts (K0) ----------------
__global__ __launch_bounds__(256) void prep_kernel(
    const float* __restrict__ query,
    const float* __restrict__ W_attn, const float* __restrict__ W_box,
    const float* __restrict__ b_attn, const float* __restrict__ b_box,
    float* __restrict__ logits, int MQ,
    const float* __restrict__ W_value, unsigned short* __restrict__ wvbf,
    const float* __restrict__ W_out, unsigned short* __restrict__ wobf)
{
    const int blk = blockIdx.x, tid = threadIdx.x;
    if (blk < 512) {
        const int K = 256, N = 256, M = MQ;
        __shared__ float As[16][68];
        __shared__ float Bs[16][68];
        int tcol = tid & 15, trow = tid >> 4;
        int m0 = (blk & 127) * 64, n0 = (blk >> 7) * 64;
        int lr = tid >> 2, lc = (tid & 3) << 2;
        float acc[4][4] = {};
        for (int k0 = 0; k0 < K; k0 += 16) {
            int arow = m0 + lr; if (arow > M - 1) arow = M - 1;
            float4 av = *(const float4*)(query + (size_t)arow * K + k0 + lc);
            int r = n0 + lr;
            float4 wv;
            if (r < 200)      wv = *(const float4*)(W_attn + (size_t)r * 256 + k0 + lc);
            else if (r < 240) wv = *(const float4*)(W_box + (size_t)(r - 200) * 256 + k0 + lc);
            else              wv = make_float4(0.f, 0.f, 0.f, 0.f);
            __syncthreads();
            As[lc + 0][lr] = av.x; As[lc + 1][lr] = av.y; As[lc + 2][lr] = av.z; As[lc + 3][lr] = av.w;
            Bs[lc + 0][lr] = wv.x; Bs[lc + 1][lr] = wv.y; Bs[lc + 2][lr] = wv.z; Bs[lc + 3][lr] = wv.w;
            __syncthreads();
#pragma unroll
            for (int k = 0; k < 16; ++k) {
                float4 a4 = *(const float4*)&As[k][trow << 2];
                float4 b4 = *(const float4*)&Bs[k][tcol << 2];
                float a[4] = {a4.x, a4.y, a4.z, a4.w};
                float bb[4] = {b4.x, b4.y, b4.z, b4.w};
#pragma unroll
                for (int i = 0; i < 4; i++)
#pragma unroll
                    for (int j = 0; j < 4; j++) acc[i][j] += a[i] * bb[j];
            }
        }
#pragma unroll
        for (int i = 0; i < 4; i++) {
            int m = m0 + trow * 4 + i;
            if (m >= M) continue;
#pragma unroll
            for (int j = 0; j < 4; j++) {
                int n = n0 + tcol * 4 + j;
                float bb = n < 200 ? b_attn[n] : (n < 240 ? b_box[n - 200] : 0.f);
                logits[(size_t)m * N + n] = acc[i][j] + bb;
            }
        }
    } else if (blk < 528) {
        int base = (blk - 512) * 1024 + tid;
#pragma unroll
        for (int k = 0; k < 4; ++k) {
            int j = base + k * 256;
            float4 f = ((const float4*)W_value)[j];
            ((uint2*)wvbf)[j] = make_uint2(pack2(f.x, f.y), pack2(f.z, f.w));
        }
    } else {
        int base = (blk - 528) * 1024 + tid;
#pragma unroll
        for (int k = 0; k < 4; ++k) {
            int j = base + k * 256;
            float4 f = ((const float4*)W_out)[j];
            ((uint2*)wobf)[j] = make_uint2(pack2(f.x, f.y), pack2(f.z, f.w));
        }
    }
}

// ---------------- K1: byte-minimal B-resident value projection (r16) ----------------
// Vout = value(M x 256 fp32) @ wvbf(256x256 bf16)^T + b_value, head-major bf16.
// 512 thr = 8 waves (wm=wv&1 m-half of 32 rows, wn=wv>>1 n-quarter of 64).
__global__ __launch_bounds__(512) void gemm_vproj(
    const float* __restrict__ A,
    const unsigned short* __restrict__ Bw,
    const float* __restrict__ bias,
    unsigned short* __restrict__ Vout, int M, int LV)
{
    __shared__ unsigned short Bres[256 * 256];   // 131072 B
    __shared__ unsigned short As[2][64 * 64];    // 2 x 8192 B
    const int tid = threadIdx.x;
    const int wv = tid >> 6, lane = tid & 63;
    const int lr = lane & 15, lq = lane >> 4;
    const int wm = wv & 1, wn = wv >> 1;
    const int rowA = tid >> 3;          // 0..63 (A staging row)
    const int gA = tid & 7;             // A staging granule (source col group)
    const int gAsw = gA ^ (rowA & 7);   // swizzled dest granule

    // ---- B resident stage: 8192 granules via async16, pre-swizzled source ----
#pragma unroll
    for (int j = 0; j < 16; ++j) {
        int G = j * 512 + tid;           // = j*512 + wv*64 + lane
        int row = G >> 5, g = G & 31;
        async16(Bw + (size_t)row * 256 + (g ^ (row & 7)) * 8,
                (char*)Bres + j * 8192 + wv * 1024);   // + lane*16 by HW
    }

    const int niter = (M + 63) / 64;
    const int stride = gridDim.x;

    // ---- prologue: A(it0, kc=0) regs -> pack -> As[0] ----
    int it0 = blockIdx.x;
    float4 pf0, pf1;
    {
        int ra = it0 * 64 + rowA; ra = ra < M ? ra : M - 1;
        const float* ap = A + (size_t)ra * 256 + gA * 8;
        pf0 = *(const float4*)ap; pf1 = *(const float4*)(ap + 4);
        uint4 pv = make_uint4(pack2(pf0.x, pf0.y), pack2(pf0.z, pf0.w),
                              pack2(pf1.x, pf1.y), pack2(pf1.z, pf1.w));
        *(uint4*)((char*)As[0] + rowA * 128 + gAsw * 16) = pv;
    }
    __syncthreads();   // drains B asyncs + A ds_writes

    int buf = 0;
    for (int it = it0; it < niter; it += stride) {
        const int m0 = it * 64;
        floatx4 acc[2][4];
#pragma unroll
        for (int i = 0; i < 2; ++i)
#pragma unroll
            for (int j = 0; j < 4; ++j) acc[i][j] = (floatx4){0.f, 0.f, 0.f, 0.f};

#pragma unroll
        for (int kc = 0; kc < 4; ++kc) {
            // ---- prefetch next A phase (kc+1, or next iter kc=0) ----
            int nit = it, nkc = kc + 1;
            if (nkc == 4) { nkc = 0; nit = it + stride; if (nit >= niter) nit = it; }
            {
                int ra = nit * 64 + rowA; ra = ra < M ? ra : M - 1;
                const float* ap = A + (size_t)ra * 256 + nkc * 64 + gA * 8;
                pf0 = *(const float4*)ap; pf1 = *(const float4*)(ap + 4);
            }
            // ---- compute on As[buf] x Bres[kc panel] ----
#pragma unroll
            for (int kb = 0; kb < 2; ++kb) {
                shortx8 af[2], bfr[4];
#pragma unroll
                for (int t = 0; t < 2; ++t) {
                    int arow = wm * 32 + t * 16 + lr;
                    af[t] = *(const shortx8*)((const char*)As[buf] + arow * 128 +
                                              (((kb * 4 + lq) ^ (arow & 7)) * 16));
                }
#pragma unroll
                for (int t = 0; t < 4; ++t) {
                    int brow = wn * 64 + t * 16 + lr;
                    int gg = kc * 8 + kb * 4 + lq;
                    bfr[t] = *(const shortx8*)((const char*)Bres + brow * 512 +
                                               ((gg ^ (brow & 7)) * 16));
                }
#pragma unroll
                for (int ti = 0; ti < 2; ++ti)
#pragma unroll
                    for (int tj = 0; tj < 4; ++tj)
                        acc[ti][tj] = __builtin_amdgcn_mfma_f32_16x16x32_bf16(bfr[tj], af[ti], acc[ti][tj], 0, 0, 0);
            }
            // ---- pack + write next A phase into As[buf^1] ----
            {
                uint4 pv = make_uint4(pack2(pf0.x, pf0.y), pack2(pf0.z, pf0.w),
                                      pack2(pf1.x, pf1.y), pack2(pf1.z, pf1.w));
                *(uint4*)((char*)As[buf ^ 1] + rowA * 128 + gAsw * 16) = pv;
            }
            __syncthreads();
            buf ^= 1;
        }
        // ---- epilogue: head-major bf16 store (transposed D) ----
#pragma unroll
        for (int ti = 0; ti < 2; ++ti) {
            int m = m0 + wm * 32 + ti * 16 + lr;
            if (m >= M) continue;
            int b = m >= LV ? 1 : 0;
            int lv = m - (b ? LV : 0);
#pragma unroll
            for (int tj = 0; tj < 4; ++tj) {
                int nb = wn * 64 + tj * 16 + lq * 4;
                float4 bv = *(const float4*)(bias + nb);
                int h = nb >> 5, dh = nb & 31;
                unsigned short* dst = Vout + ((size_t)(b * 8 + h) * LV + lv) * 32 + dh;
                *(uint2*)dst = make_uint2(pack2(acc[ti][tj][0] + bv.x, acc[ti][tj][1] + bv.y),
                                          pack2(acc[ti][tj][2] + bv.z, acc[ti][tj][3] + bv.w));
            }
        }
    }
}

// ---------------- K3: XCD-temporal fused decode + gather, 16 q/block ----------------
// grid (16, LQ/16) = 4096 blocks x 512 thr. Same per-q math as the 8q version
// (bitwise identical); per-block fixed costs amortized 2x.
__global__ __launch_bounds__(512) void decode_sample_kernel(
    const unsigned short* __restrict__ v,   // bf16 [b*8+h][LV][32]
    const float* __restrict__ logits,       // MQ x 256 (240 real)
    const float* __restrict__ ref_windows,  // MQ x 7
    float* __restrict__ attn_out,           // MQ x 200
    unsigned short* __restrict__ ohbf,      // MQ x 256 bf16
    const int* __restrict__ Hf_p, const int* __restrict__ Wf_p, int LV, int LQ)
{
    __shared__ float lg[16][32];
    __shared__ float rw[16][7];
    __shared__ float prm[16][6];
    __shared__ float mxinv[16][2];
    __shared__ uint4 pk[16][25][2];

    const int lin = blockIdx.y * 16 + blockIdx.x;
    const int nc = gridDim.y;               // LQ/16
    const int seq = lin >> 3;
    const int c = seq % nc;
    const int s = (lin & 7) + ((seq / nc) << 3);
    const int b = s >> 3, h = s & 7;
    const int tid = threadIdx.x;
    const int Hf = *Hf_p, Wf = *Wf_p;
    const size_t mbase = (size_t)b * LQ + c * 16;

    if (tid < 480) {
        int qq = tid / 30, j = tid - qq * 30;
        int col = (j < 25) ? h * 25 + j : 200 + h * 5 + (j - 25);
        lg[qq][j] = logits[(mbase + qq) * 256 + col];
    }
    if (tid < 112) {
        int qq = tid / 7, k = tid - qq * 7;
        rw[qq][k] = ref_windows[(mbase + qq) * 7 + k];
    }
    __syncthreads();

    if (tid < 16) {
        int qq = tid;
        float mx = -1e30f;
#pragma unroll
        for (int p = 0; p < 25; p++) mx = fmaxf(mx, lg[qq][p]);
        float ssum = 0.f;
#pragma unroll
        for (int p = 0; p < 25; p++) ssum += expf(lg[qq][p] - mx);
        mxinv[qq][0] = mx; mxinv[qq][1] = 1.f / ssum;
        float cx = rw[qq][0] + lg[qq][25] * 0.125f * rw[qq][3];
        float cy = rw[qq][1] + lg[qq][26] * 0.125f * rw[qq][4];
        float bw = rw[qq][3] + lg[qq][27] * 0.125f * rw[qq][3];
        float bh = rw[qq][4] + lg[qq][28] * 0.125f * rw[qq][4];
        float ang = (rw[qq][6] + lg[qq][29] * 0.0625f) * 6.283185307179586f;
        prm[qq][0] = cx; prm[qq][1] = cy;
        prm[qq][2] = fmaxf(bw, 0.f); prm[qq][3] = fmaxf(bh, 0.f);
        prm[qq][4] = cosf(ang); prm[qq][5] = sinf(ang);
    }
    __syncthreads();

    if (tid < 400) {
        int qq = tid / 25, p = tid - qq * 25;
        float a = expf(lg[qq][p] - mxinv[qq][0]) * mxinv[qq][1];
        attn_out[(mbase + qq) * 200 + h * 25 + p] = a;
        int pi = p / 5, pj = p - pi * 5;
        float g0 = (float)(pj - 2) * 0.2f * prm[qq][2];
        float g1 = (float)(pi - 2) * 0.2f * prm[qq][3];
        float ca = prm[qq][4], sa = prm[qq][5];
        float gx = (prm[qq][0] + g0 * ca - g1 * sa) * (float)Wf - 0.5f;
        float gy = (prm[qq][1] + g0 * sa + g1 * ca) * (float)Hf - 0.5f;
        float x0f = floorf(gx), y0f = floorf(gy);
        int x0 = (int)x0f, y0 = (int)y0f;
        float wx1 = gx - x0f, wy1 = gy - y0f;
        float wx0 = 1.f - wx1, wy0 = 1.f - wy1;
        int y1 = y0 + 1;
        int bx; float wl, wr;
        if (x0 >= 0 && x0 <= Wf - 2)      { bx = x0;     wl = wx0; wr = wx1; }
        else if (x0 == -1)                { bx = 0;      wl = wx1; wr = 0.f; }
        else if (x0 == Wf - 1)            { bx = Wf - 2; wl = 0.f; wr = wx0; }
        else                              { bx = 0;      wl = 0.f; wr = 0.f; }
        float wy0v = (y0 >= 0 && y0 < Hf) ? wy0 : 0.f;
        float wy1v = (y1 >= 0 && y1 < Hf) ? wy1 : 0.f;
        int cy0 = min(max(y0, 0), Hf - 1), cy1 = min(max(y1, 0), Hf - 1);
        unsigned off0 = (unsigned)(cy0 * Wf + bx) * 16u;
        unsigned off1 = (unsigned)(cy1 * Wf + bx) * 16u;
        float aw0 = a * wy0v, aw1 = a * wy1v;
        pk[qq][p][0] = make_uint4(__float_as_uint(aw0 * wl), __float_as_uint(aw1 * wl), off0, off1);
        pk[qq][p][1] = make_uint4(__float_as_uint(aw0 * wr), __float_as_uint(aw1 * wr), off0, off1);
    }
    __syncthreads();

    const int qq = tid >> 5, l = tid & 31;
    const unsigned int* vw = (const unsigned int*)(v + (size_t)s * LV * 32);
    const uint4* pkp = &pk[qq][0][l >> 4];
    float e0 = 0.f, o0 = 0.f, e1 = 0.f, o1 = 0.f;
#pragma unroll
    for (int p = 0; p < 25; ++p) {
        uint4 t = pkp[2 * p];
        float w0 = __uint_as_float(t.x), w1 = __uint_as_float(t.y);
        unsigned u0 = vw[t.z + l];
        unsigned u1 = vw[t.w + l];
        e0 += w0 * __uint_as_float(u0 << 16);
        o0 += w0 * __uint_as_float(u0 & 0xffff0000u);
        e1 += w1 * __uint_as_float(u1 << 16);
        o1 += w1 * __uint_as_float(u1 & 0xffff0000u);
    }
    float a0 = e0 + e1, a1 = o0 + o1;
    a0 += __shfl_xor(a0, 16, 32);
    a1 += __shfl_xor(a1, 16, 32);
    if (l < 16)
        ((unsigned int*)ohbf)[(mbase + qq) * 128 + h * 16 + l] = pack2(a0, a1);
}

// ---------------- K4: bf16 MFMA GEMM (round-11 verified, BM=64) ----------------
__global__ __launch_bounds__(256) void gemm_out(
    const unsigned short* __restrict__ Ab,
    const unsigned short* __restrict__ Bw,
    const float* __restrict__ bias,
    float* __restrict__ C, int M)
{
    constexpr int BM = 64;
    constexpr int NI = BM / 32, TI = BM / 32;
    __shared__ unsigned short As[2][BM * 64];
    __shared__ unsigned short Bs[2][128 * 64];
    const int tid = threadIdx.x;
    const int wv = tid >> 6, lane = tid & 63;
    const int lr = lane & 15, lq = lane >> 4;
    const int m0 = blockIdx.x * BM, n0 = blockIdx.y * 128;
    const int wm = wv & 1, wn = wv >> 1;
    const int srow = tid >> 3;
    const int colg = tid & 7;
    const int colgSw = colg ^ (srow & 7);

    floatx4 acc[TI][4];
#pragma unroll
    for (int i = 0; i < TI; ++i)
#pragma unroll
        for (int j = 0; j < 4; ++j) acc[i][j] = (floatx4){0.f, 0.f, 0.f, 0.f};

    auto compute = [&](const unsigned short* Acur, const unsigned short* Bcur) {
#pragma unroll
        for (int kb = 0; kb < 2; ++kb) {
            shortx8 af[TI], bfr[4];
#pragma unroll
            for (int t = 0; t < TI; ++t) {
                int arow = wm * (BM / 2) + t * 16 + lr;
                af[t] = *(const shortx8*)&Acur[arow * 64 + (((kb * 4 + lq) ^ (arow & 7)) * 8)];
            }
#pragma unroll
            for (int t = 0; t < 4; ++t) {
                int brow = wn * 64 + t * 16 + lr;
                bfr[t] = *(const shortx8*)&Bcur[brow * 64 + (((kb * 4 + lq) ^ (brow & 7)) * 8)];
            }
#pragma unroll
            for (int ti = 0; ti < TI; ++ti)
#pragma unroll
                for (int tj = 0; tj < 4; ++tj)
                    acc[ti][tj] = __builtin_amdgcn_mfma_f32_16x16x32_bf16(bfr[tj], af[ti], acc[ti][tj], 0, 0, 0);
        }
    };

#pragma unroll
    for (int i = 0; i < NI; ++i) {
        int ra = m0 + i * 32 + srow; ra = ra < M ? ra : M - 1;
        async16(Ab + (size_t)ra * 256 + colgSw * 8, (char*)As[0] + i * 4096 + wv * 1024);
    }
#pragma unroll
    for (int i = 0; i < 4; ++i) {
        int rb = n0 + i * 32 + srow;
        async16(Bw + (size_t)rb * 256 + colgSw * 8, (char*)Bs[0] + i * 4096 + wv * 1024);
    }
    __syncthreads();
    int cur = 0;
    for (int kc = 0; kc < 4; ++kc) {
        const int nk = (kc + 1) * 64;
        if (kc < 3) {
#pragma unroll
            for (int i = 0; i < NI; ++i) {
                int ra = m0 + i * 32 + srow; ra = ra < M ? ra : M - 1;
                async16(Ab + (size_t)ra * 256 + nk + colgSw * 8,
                        (char*)As[cur ^ 1] + i * 4096 + wv * 1024);
            }
#pragma unroll
            for (int i = 0; i < 4; ++i) {
                int rb = n0 + i * 32 + srow;
                async16(Bw + (size_t)rb * 256 + nk + colgSw * 8,
                        (char*)Bs[cur ^ 1] + i * 4096 + wv * 1024);
            }
        }
        compute(As[cur], Bs[cur]);
        __syncthreads();
        cur ^= 1;
    }
#pragma unroll
    for (int ti = 0; ti < TI; ++ti) {
        int m = m0 + wm * (BM / 2) + ti * 16 + lr;
        if (m >= M) continue;
        float* Crow = C + (size_t)m * 256;
#pragma unroll
        for (int tj = 0; tj < 4; ++tj) {
            int nb = n0 + wn * 64 + tj * 16 + lq * 4;
            float4 bv = *(const float4*)(bias + nb);
            float4 o = make_float4(acc[ti][tj][0] + bv.x, acc[ti][tj][1] + bv.y,
                                   acc[ti][tj][2] + bv.z, acc[ti][tj][3] + bv.w);
            *(float4*)(Crow + nb) = o;
        }
    }
}

extern "C" void kernel_launch(void* const* d_in, const int* in_sizes, int n_in,
                              void* d_out, int out_size, void* d_ws, size_t ws_size,
                              hipStream_t stream) {
    const float* query       = (const float*)d_in[0];
    const float* value       = (const float*)d_in[1];
    const float* ref_windows = (const float*)d_in[2];
    const float* W_box       = (const float*)d_in[3];
    const float* b_box       = (const float*)d_in[4];
    const float* W_attn      = (const float*)d_in[5];
    const float* b_attn      = (const float*)d_in[6];
    const float* W_value     = (const float*)d_in[7];
    const float* b_value     = (const float*)d_in[8];
    const float* W_out       = (const float*)d_in[9];
    const float* b_out       = (const float*)d_in[10];
    const int*   Hf          = (const int*)d_in[11];
    const int*   Wf          = (const int*)d_in[12];

    const int M1 = in_sizes[1] / 256;  // B*LV = 70688
    const int MQ = in_sizes[0] / 256;  // B*LQ = 8192
    const int LQ = MQ / 2;
    const int LV = M1 / 2;

    unsigned short* Vout = (unsigned short*)d_ws;                 // M1*256
    unsigned short* ohbf = Vout + (size_t)M1 * 256;               // MQ*256
    unsigned short* wvbf = ohbf + (size_t)MQ * 256;               // 65536
    unsigned short* wobf = wvbf + 65536;                          // 65536
    float* logits    = (float*)(wobf + 65536);                    // MQ*256

    float* out0     = (float*)d_out;
    float* attn_out = out0 + (size_t)MQ * 256;

    // P: fused logits (512 blocks) + weight converts (32 blocks)
    prep_kernel<<<544, 256, 0, stream>>>(query, W_attn, W_box, b_attn, b_box,
                                         logits, MQ, W_value, wvbf, W_out, wobf);
    // K1: byte-minimal B-resident value projection (256 blocks = 1/CU)
    gemm_vproj<<<256, 512, 0, stream>>>(value, wvbf, b_value, Vout, M1, LV);
    // K3: XCD-temporal fused softmax + box decode + gather, 16 q/block
    decode_sample_kernel<<<dim3(16, LQ / 16), 512, 0, stream>>>(
        Vout, logits, ref_windows, attn_out, ohbf, Hf, Wf, LV, LQ);
    // K4: output projection (round-11 verified LDS dbuf kernel)
    dim3 g4(MQ / 64, 2);
    gemm_out<<<g4, 256, 0, stream>>>(ohbf, wobf, b_out, out0, MQ);
}